// Round 19
// baseline (1641.995 us; speedup 1.0000x reference)
//
#include <hip/hip_runtime.h>
#include <hip/hip_bf16.h>
#include <math.h>

#define NSEQ 2048
#define NDIM 768
#define NLAY 8
#define NHEAD 6
#define NHD 128
#define NVOC 50257
#define NBLK 16
#define BLKSZ 128
#define EOS_TOK 50256
#define EPSF 1.1920929e-07f
#define ASCALE 0.12f
#define NVT 393   // ceil(50257/128) vocab tiles
#define CAPSH 15.f   // fixed LSE shift for logits: softcap output bounded in (-15,15)
#define ATTSH 15.5f  // fixed shift for attention scores: |q.k|*0.12 <= 15.46 (rms rows)

// granule swizzle for 64B-row LDS tiles (4 x 16B granules/row)
#define GSWZ(r) (((r) ^ ((r) >> 2)) & 3)

using bf16x8 = __attribute__((ext_vector_type(8))) __bf16;
using bf16x4 = __attribute__((ext_vector_type(4))) __bf16;
using f32x4  = __attribute__((ext_vector_type(4))) float;

__device__ __forceinline__ __bf16 tobf(float x) {
  __hip_bfloat16 h = __float2bfloat16(x);
  return *reinterpret_cast<__bf16*>(&h);
}
__device__ __forceinline__ float frombf(__bf16 x) {
  __hip_bfloat16 h = *reinterpret_cast<__hip_bfloat16*>(&x);
  return __bfloat162float(h);
}

// ---------------- f32 -> bf16 bulk convert ----------------
__global__ __launch_bounds__(256) void cvt_bf16_kernel(const float* __restrict__ in, __bf16* __restrict__ out,
                                                       long n) {
  long i = ((long)blockIdx.x * blockDim.x + threadIdx.x) * 4;
  long stride = (long)gridDim.x * blockDim.x * 4;
  for (; i < n; i += stride) {
    float4 v = *(const float4*)(in + i);
    bf16x4 o;
    o[0] = tobf(v.x); o[1] = tobf(v.y); o[2] = tobf(v.z); o[3] = tobf(v.w);
    *(bf16x4*)(out + i) = o;
  }
}

// ---------------- prep: docs cumsum + block mask categories ----------------
__global__ __launch_bounds__(1024) void prep_kernel(const int* __restrict__ seq, const int* __restrict__ wptr,
                                                    int* __restrict__ docs, int* __restrict__ catL,
                                                    int* __restrict__ catS) {
  __shared__ int f[NSEQ];
  __shared__ int g[NSEQ];
  int tid = threadIdx.x;
  for (int i = tid; i < NSEQ; i += 1024) f[i] = (seq[i] == EOS_TOK) ? 1 : 0;
  __syncthreads();
  int* a = f; int* b = g;
  for (int off = 1; off < NSEQ; off <<= 1) {
    for (int i = tid; i < NSEQ; i += 1024) {
      int v = a[i];
      if (i >= off) v += a[i - off];
      b[i] = v;
    }
    __syncthreads();
    int* t = a; a = b; b = t;
  }
  for (int i = tid; i < NSEQ; i += 1024) docs[i] = a[i];
  __syncthreads();
  if (tid == 0) {
    int dl[NBLK], dh[NBLK];
    for (int bi = 0; bi < NBLK; ++bi) { dl[bi] = a[bi * BLKSZ]; dh[bi] = a[bi * BLKSZ + BLKSZ - 1]; }
    int W = *wptr;
    for (int pass = 0; pass < 2; ++pass) {
      int w = (pass == 0) ? W : (W / 2);
      int* cat = (pass == 0) ? catL : catS;
      for (int i = 0; i < NBLK; ++i) {
        int allr[NBLK], partr[NBLK];
        int nf = 0, np = 0;
        for (int j = 0; j < NBLK; ++j) {
          int any_ = (i >= j) && (dl[i] <= dh[j]) && (dh[i] >= dl[j]);
          int all_ = (i > j) && (dl[i] == dh[j]) && (dh[i] == dl[j]);
          allr[j] = all_; partr[j] = any_ && !all_;
          nf += all_; np += partr[j];
        }
        int kcf = min(nf, w - 1);
        int kcp = min(np, max(w - nf, 1));
        int cf = 0, cp = 0;
        for (int j = NBLK - 1; j >= 0; --j) {
          int cv = 0;
          if (allr[j]) { cf++; if (cf <= kcf) cv = 2; }
          if (partr[j]) { cp++; if (cp <= kcp) cv = 1; }
          cat[i * NBLK + j] = cv;
        }
      }
    }
  }
}

// ---------------- embedding gather + rms -> x, x0 ----------------
__global__ __launch_bounds__(256) void embed_rms_kernel(const int* __restrict__ seq, const float* __restrict__ embed,
                                                        float* __restrict__ x, float* __restrict__ x0) {
  int s = blockIdx.x;
  int tid = threadIdx.x;
  const float* row = embed + (size_t)seq[s] * NDIM;
  float v0 = row[tid], v1 = row[tid + 256], v2 = row[tid + 512];
  float ss = v0 * v0 + v1 * v1 + v2 * v2;
  __shared__ float red[256];
  red[tid] = ss; __syncthreads();
  for (int o = 128; o > 0; o >>= 1) { if (tid < o) red[tid] += red[tid + o]; __syncthreads(); }
  float sc = rsqrtf(red[0] / (float)NDIM + EPSF);
  size_t base = (size_t)s * NDIM;
  float o0 = v0 * sc, o1 = v1 * sc, o2 = v2 * sc;
  x[base + tid] = o0; x[base + tid + 256] = o1; x[base + tid + 512] = o2;
  x0[base + tid] = o0; x0[base + tid + 256] = o1; x0[base + tid + 512] = o2;
}

// ---------------- row rms -> bf16 ----------------
__global__ __launch_bounds__(256) void rmsbf_kernel(const float* __restrict__ x, __bf16* __restrict__ xb) {
  int s = blockIdx.x;
  int tid = threadIdx.x;
  size_t base = (size_t)s * NDIM;
  float v0 = x[base + tid], v1 = x[base + tid + 256], v2 = x[base + tid + 512];
  float ss = v0 * v0 + v1 * v1 + v2 * v2;
  __shared__ float red[256];
  red[tid] = ss; __syncthreads();
  for (int o = 128; o > 0; o >>= 1) { if (tid < o) red[tid] += red[tid + o]; __syncthreads(); }
  float sc = rsqrtf(red[0] / (float)NDIM + EPSF);
  xb[base + tid] = tobf(v0 * sc); xb[base + tid + 256] = tobf(v1 * sc); xb[base + tid + 512] = tobf(v2 * sc);
}

// ---------------- fused residual mix + rms->bf16 ----------------
__global__ __launch_bounds__(256) void mixrms_kernel(float* __restrict__ x, const float* __restrict__ x0,
                                                     const float* __restrict__ skip, const float* __restrict__ scal,
                                                     int li, int sj, __bf16* __restrict__ xb) {
  float lam0 = scal[NLAY + 2 * li], lam1 = scal[NLAY + 2 * li + 1];
  float sw = (sj >= 0) ? scal[sj] : 0.f;
  int s = blockIdx.x;
  int tid = threadIdx.x;
  size_t base = (size_t)s * NDIM;
  float xv[3], ov[3], nv[3];
  xv[0] = x[base + tid]; xv[1] = x[base + tid + 256]; xv[2] = x[base + tid + 512];
  ov[0] = x0[base + tid]; ov[1] = x0[base + tid + 256]; ov[2] = x0[base + tid + 512];
  if (skip) {
    nv[0] = lam0 * (xv[0] + sw * skip[base + tid])       + lam1 * ov[0];
    nv[1] = lam0 * (xv[1] + sw * skip[base + tid + 256]) + lam1 * ov[1];
    nv[2] = lam0 * (xv[2] + sw * skip[base + tid + 512]) + lam1 * ov[2];
  } else {
    nv[0] = lam0 * xv[0] + lam1 * ov[0];
    nv[1] = lam0 * xv[1] + lam1 * ov[1];
    nv[2] = lam0 * xv[2] + lam1 * ov[2];
  }
  x[base + tid] = nv[0]; x[base + tid + 256] = nv[1]; x[base + tid + 512] = nv[2];
  float ss = nv[0] * nv[0] + nv[1] * nv[1] + nv[2] * nv[2];
  __shared__ float red[256];
  red[tid] = ss; __syncthreads();
  for (int o = 128; o > 0; o >>= 1) { if (tid < o) red[tid] += red[tid + o]; __syncthreads(); }
  float sc = rsqrtf(red[0] / (float)NDIM + EPSF);
  xb[base + tid] = tobf(nv[0] * sc); xb[base + tid + 256] = tobf(nv[1] * sc); xb[base + tid + 512] = tobf(nv[2] * sc);
}

// ---------------- bf16 MFMA GEMM 64x64, BK=64, global_load_lds dbuf, swizzled LDS ---------
// MODE 0: store f32; 1: += f32; 2: relu^2->bf16; 3: store bf16; 4: += f32 AND copy to Sk.
template <int MODE>
__global__ __launch_bounds__(256) void gemm_mfma64(const __bf16* __restrict__ A, const __bf16* __restrict__ B,
                                                   float* __restrict__ Cf, __bf16* __restrict__ Cb,
                                                   float* __restrict__ Sk, int N, int K) {
  __shared__ __bf16 As[2][64 * 64];
  __shared__ __bf16 Bs[2][64 * 64];
  int bm = blockIdx.x * 64, bn = blockIdx.y * 64;
  int tid = threadIdx.x;
  int w = tid >> 6, l = tid & 63;
  int wm = (w >> 1) * 32, wn = (w & 1) * 32;
  int c = l & 15, g = l >> 4;

  auto stage = [&](int buf, int k0) {
#pragma unroll
    for (int i = 0; i < 2; ++i) {
      int L = (w * 2 + i) * 64 + l;   // granule 0..511
      int row = L >> 3, gl = L & 7;
      int gs = gl ^ (row & 7);
      const __bf16* srcA = A + (size_t)(bm + row) * K + k0 + gs * 8;
      const __bf16* srcB = B + (size_t)(bn + row) * K + k0 + gs * 8;
      __builtin_amdgcn_global_load_lds(
          (const __attribute__((address_space(1))) void*)srcA,
          (__attribute__((address_space(3))) void*)&As[buf][(w * 2 + i) * 512], 16, 0, 0);
      __builtin_amdgcn_global_load_lds(
          (const __attribute__((address_space(1))) void*)srcB,
          (__attribute__((address_space(3))) void*)&Bs[buf][(w * 2 + i) * 512], 16, 0, 0);
    }
  };

  f32x4 acc[2][2] = {};
  stage(0, 0);
  __syncthreads();
  int nk = K >> 6;
  for (int kk = 0; kk < nk; ++kk) {
    int buf = kk & 1;
    if (kk + 1 < nk) stage(buf ^ 1, (kk + 1) * 64);
#pragma unroll
    for (int ks = 0; ks < 2; ++ks) {
      bf16x8 af[2], bfr[2];
#pragma unroll
      for (int i = 0; i < 2; ++i) {
        int row = wm + i * 16 + c;
        af[i] = *(const bf16x8*)&As[buf][row * 64 + ((ks * 4 + g) ^ (row & 7)) * 8];
      }
#pragma unroll
      for (int j = 0; j < 2; ++j) {
        int row = wn + j * 16 + c;
        bfr[j] = *(const bf16x8*)&Bs[buf][row * 64 + ((ks * 4 + g) ^ (row & 7)) * 8];
      }
#pragma unroll
      for (int i = 0; i < 2; ++i)
#pragma unroll
        for (int j = 0; j < 2; ++j)
          acc[i][j] = __builtin_amdgcn_mfma_f32_16x16x32_bf16(af[i], bfr[j], acc[i][j], 0, 0, 0);
    }
    __syncthreads();
  }
#pragma unroll
  for (int i = 0; i < 2; ++i)
#pragma unroll
    for (int j = 0; j < 2; ++j)
#pragma unroll
      for (int rr = 0; rr < 4; ++rr) {
        int row = bm + wm + i * 16 + g * 4 + rr;
        int col = bn + wn + j * 16 + c;
        size_t ci = (size_t)row * N + col;
        float z = acc[i][j][rr];
        if (MODE == 0) Cf[ci] = z;
        else if (MODE == 1) Cf[ci] += z;
        else if (MODE == 2) { float r = fmaxf(z, 0.f); Cb[ci] = tobf(r * r); }
        else if (MODE == 3) Cb[ci] = tobf(z);
        else { float s = Cf[ci] + z; Cf[ci] = s; Sk[ci] = s; }
      }
}

// ---------------- qkv post: wave per (s,h); bf16 in, bf16 q,k,v out ----------------
__global__ __launch_bounds__(256) void qkv_post_kernel(const __bf16* __restrict__ qkv, const float* __restrict__ vemb,
                                                       const int* __restrict__ seq, const float* __restrict__ scal,
                                                       int li, int ve_idx,
                                                       __bf16* __restrict__ qo, __bf16* __restrict__ ko,
                                                       __bf16* __restrict__ vo) {
  int p = blockIdx.x * 4 + (threadIdx.x >> 6);  // p = h*NSEQ + s
  int l = threadIdx.x & 63;
  int h = p >> 11;
  int s = p & (NSEQ - 1);
  float sal0 = scal[3 * NLAY + 2 * li], sal1 = scal[3 * NLAY + 2 * li + 1];
  float fr = (l < 32) ? powf(1.0f / 1024.0f, (float)l * (1.0f / 31.0f)) : 0.f;
  float th = (float)s * fr;
  float cth = cosf(th), sth = sinf(th);
  size_t rb = (size_t)s * (3 * NHEAD * NHD) + h * NHD;
  float q0 = frombf(qkv[rb + l]),                 q1 = frombf(qkv[rb + l + 64]);
  float k0 = frombf(qkv[rb + NHEAD * NHD + l]),   k1 = frombf(qkv[rb + NHEAD * NHD + l + 64]);
  float v0 = frombf(qkv[rb + 2 * NHEAD * NHD + l]), v1 = frombf(qkv[rb + 2 * NHEAD * NHD + l + 64]);
  float ssq = q0 * q0 + q1 * q1;
  float ssk = k0 * k0 + k1 * k1;
#pragma unroll
  for (int o = 1; o < 64; o <<= 1) {
    ssq += __shfl_xor(ssq, o, 64);
    ssk += __shfl_xor(ssk, o, 64);
  }
  float scq = rsqrtf(ssq / (float)NHD + EPSF);
  float sck = rsqrtf(ssk / (float)NHD + EPSF);
  float qn0 = q0 * scq, qn1 = q1 * scq;
  float kn0 = k0 * sck, kn1 = k1 * sck;
  float oq0 = qn0 * cth + qn1 * sth, oq1 = -qn0 * sth + qn1 * cth;
  float ok0 = kn0 * cth + kn1 * sth, ok1 = -kn0 * sth + kn1 * cth;
  float ov0 = sal0 * v0, ov1 = sal0 * v1;
  if (ve_idx >= 0) {
    const float* ver = vemb + ((size_t)ve_idx * NVOC + seq[s]) * NDIM + h * NHD;
    ov0 += sal1 * ver[l];
    ov1 += sal1 * ver[l + 64];
  }
  size_t oo = ((size_t)h * NSEQ + s) * NHD;
  qo[oo + l] = tobf(oq0); qo[oo + l + 64] = tobf(oq1);
  ko[oo + l] = tobf(ok0); ko[oo + l + 64] = tobf(ok1);
  vo[oo + l] = tobf(ov0); vo[oo + l + 64] = tobf(ov1);
}

// ---------------- V transpose: [h][s][d] -> [h][d][s] (bf16) ----------------
__global__ __launch_bounds__(256) void vtrans_kernel(const __bf16* __restrict__ v, __bf16* __restrict__ vt) {
  int st = blockIdx.x * 64, dt = blockIdx.y * 64, h = blockIdx.z;
  __shared__ __bf16 t[64][65];
  int tid = threadIdx.x;
  for (int e = tid; e < 4096; e += 256) {
    int s = e >> 6, d = e & 63;
    t[s][d] = v[((size_t)h * NSEQ + st + s) * NHD + dt + d];
  }
  __syncthreads();
  for (int e = tid; e < 512; e += 256) {
    int d = e >> 3, s0 = (e & 7) * 8;
    bf16x8 ov;
#pragma unroll
    for (int i = 0; i < 8; ++i) ov[i] = t[s0 + i][d];
    *(bf16x8*)(vt + ((size_t)h * NHD + dt + d) * NSEQ + st + s0) = ov;
  }
}

// ---------------- MFMA flash attention v7: 64-row q-blocks, 8 waves (2 pair x 4 sub) ------
// Each staged K/V tile consumed by 64 q-rows (2x reuse vs v6); fixed-shift softmax.
// Pair p handles tiles {i : i mod 2 == p}; 4 sub-waves per pair share one tile stream.
__global__ __launch_bounds__(512) void attn_mfma_kernel(const __bf16* __restrict__ qb, const __bf16* __restrict__ kb,
                                                        const __bf16* __restrict__ vt, const int* __restrict__ cat,
                                                        const int* __restrict__ docs, __bf16* __restrict__ y) {
  int qb64 = (int)gridDim.x - 1 - (int)blockIdx.x;   // heavy blocks first
  int h = blockIdx.y;
  int tid = threadIdx.x;
  int wq = tid >> 6;      // 0..7
  int pr = wq >> 2;       // tile-parity pair (0,1)
  int sub = wq & 3;       // q-row quarter (0..3)
  int l = tid & 63;
  int c = l & 15, g = l >> 4;
  int q0 = qb64 * 64 + sub * 16;
  int qB = qb64 >> 1;     // 128-row mask block index

  __shared__ __align__(16) char arena[65536];
  __bf16* Ks  = (__bf16*)arena;             // stream (pr*2+buf)*4096 elems (8KB)
  __bf16* Vts = (__bf16*)(arena + 32768);
  __shared__ __bf16 Ps[8][16 * 32];
  __shared__ int kvs[72];
  __shared__ int kvc[72];
  __shared__ int nact_s;

  if (tid == 0) {
    int n = 0;
    int kmax = 2 * qb64 + 1;   // last 32-key tile overlapping q-rows of this block
    for (int kv = 0; kv <= kmax; ++kv) {
      int cc = cat[qB * NBLK + (kv >> 2)];
      if (cc) { kvs[n] = kv; kvc[n] = cc; ++n; }
    }
    nact_s = n;
  }

  bf16x8 qf[4];
#pragma unroll
  for (int ks = 0; ks < 4; ++ks)
    qf[ks] = *(const bf16x8*)(qb + ((size_t)h * NSEQ + q0 + c) * NHD + ks * 32 + g * 8);

  int qd[4];
#pragma unroll
  for (int rr = 0; rr < 4; ++rr) qd[rr] = docs[q0 + g * 4 + rr];

  float lden[4] = {0.f, 0.f, 0.f, 0.f};
  f32x4 oacc[8] = {};

  __syncthreads();
  int nact = nact_s;
  int nit = (nact + 1) >> 1;

  // stage one 32-key K/V tile into pair-stream buf: 16 KB over 4 sub-waves (2+2 loads each)
  auto stage = [&](int ti, int bufi) {
    int kv = kvs[ti];
#pragma unroll
    for (int i = 0; i < 2; ++i) {
      int L = (sub * 2 + i) * 64 + l;     // granule 0..511
      int krow = L >> 4, gl = L & 15;
      int gs = gl ^ (krow & 7);
      const __bf16* srcK = kb + ((size_t)h * NSEQ + kv * 32 + krow) * NHD + gs * 8;
      __builtin_amdgcn_global_load_lds(
          (const __attribute__((address_space(1))) void*)srcK,
          (__attribute__((address_space(3))) void*)&Ks[(pr * 2 + bufi) * 4096 + (sub * 2 + i) * 512], 16, 0, 0);
      int drow = L >> 2, gk = L & 3;
      const __bf16* srcV = vt + ((size_t)h * NHD + drow) * NSEQ + kv * 32 + gk * 8;
      __builtin_amdgcn_global_load_lds(
          (const __attribute__((address_space(1))) void*)srcV,
          (__attribute__((address_space(3))) void*)&Vts[(pr * 2 + bufi) * 4096 + (sub * 2 + i) * 512], 16, 0, 0);
    }
  };

  if (pr < nact) stage(pr, 0);
  __syncthreads();

  for (int it = 0; it < nit; ++it) {
    int buf = it & 1;
    int tin = 2 * (it + 1) + pr;
    if (tin < nact) stage(tin, buf ^ 1);
    int ti = 2 * it + pr;
    if (ti < nact) {
      int kv = kvs[ti], cc = kvc[ti];
      int k0 = kv * 32;
      const __bf16* Kb = &Ks[(pr * 2 + buf) * 4096];
      const __bf16* Vb = &Vts[(pr * 2 + buf) * 4096];

      f32x4 sacc[2] = {};
#pragma unroll
      for (int ks = 0; ks < 4; ++ks) {
#pragma unroll
        for (int j = 0; j < 2; ++j) {
          int row = j * 16 + c;
          int gi = (ks * 4 + g) ^ (row & 7);
          bf16x8 kf = *(const bf16x8*)&Kb[row * 128 + gi * 8];
          sacc[j] = __builtin_amdgcn_mfma_f32_16x16x32_bf16(qf[ks], kf, sacc[j], 0, 0, 0);
        }
      }
      // fixed-shift probabilities (masked -> 0), per-row partial sum
      float sc[2][4];
      float psum[4] = {0.f, 0.f, 0.f, 0.f};
#pragma unroll
      for (int j = 0; j < 2; ++j) {
        int key = k0 + j * 16 + c;
        int kdj = docs[key];
#pragma unroll
        for (int rr = 0; rr < 4; ++rr) {
          int qrow = q0 + g * 4 + rr;
          bool ok = (cc == 2) || ((key <= qrow) && (kdj == qd[rr]));
          float pv = ok ? __expf(sacc[j][rr] * ASCALE - ATTSH) : 0.f;
          sc[j][rr] = pv;
          psum[rr] += pv;
        }
      }
#pragma unroll
      for (int rr = 0; rr < 4; ++rr) {
        psum[rr] += __shfl_xor(psum[rr], 1, 64);
        psum[rr] += __shfl_xor(psum[rr], 2, 64);
        psum[rr] += __shfl_xor(psum[rr], 4, 64);
        psum[rr] += __shfl_xor(psum[rr], 8, 64);
        lden[rr] += psum[rr];
      }
#pragma unroll
      for (int j = 0; j < 2; ++j)
#pragma unroll
        for (int rr = 0; rr < 4; ++rr)
          Ps[wq][(g * 4 + rr) * 32 + j * 16 + c] = tobf(sc[j][rr]);
      asm volatile("s_waitcnt lgkmcnt(0)" ::: "memory");
      bf16x8 pf = *(const bf16x8*)&Ps[wq][c * 32 + g * 8];
#pragma unroll
      for (int nt = 0; nt < 8; ++nt) {
        bf16x8 vf = *(const bf16x8*)&Vb[(nt * 16 + c) * 32 + g * 8];
        oacc[nt] = __builtin_amdgcn_mfma_f32_16x16x32_bf16(pf, vf, oacc[nt], 0, 0, 0);
      }
    }
    __syncthreads();
  }

  // intra-block merge: plain sums across the two parity pairs (arena K region is dead)
  float* mrg = (float*)arena;  // [sub*64+l][36]: lden[4], oacc[8][4] -> 36 KB
  if (pr == 1) {
    int base = (sub * 64 + l) * 36;
#pragma unroll
    for (int rr = 0; rr < 4; ++rr) mrg[base + rr] = lden[rr];
#pragma unroll
    for (int nt = 0; nt < 8; ++nt)
#pragma unroll
      for (int rr = 0; rr < 4; ++rr) mrg[base + 4 + nt * 4 + rr] = oacc[nt][rr];
  }
  __syncthreads();
  if (pr == 0) {
    int base = (sub * 64 + l) * 36;
    float inv[4];
#pragma unroll
    for (int rr = 0; rr < 4; ++rr) {
      float L = lden[rr] + mrg[base + rr];
      inv[rr] = (L > 0.f) ? 1.f / L : 0.f;
    }
#pragma unroll
    for (int nt = 0; nt < 8; ++nt)
#pragma unroll
      for (int rr = 0; rr < 4; ++rr) {
        int qrow = q0 + g * 4 + rr;
        float o = oacc[nt][rr] + mrg[base + 4 + nt * 4 + rr];
        y[(size_t)qrow * NDIM + h * NHD + nt * 16 + c] = tobf(o * inv[rr]);
      }
  }
}

// ---------------- logits GEMM + fused softcap/fixed-shift-LSE epilogue, XCD-swizzled ------
__global__ __launch_bounds__(256) void logits_gemm_kernel(const __bf16* __restrict__ xbf,
                                                          const __bf16* __restrict__ embed_bf,
                                                          const int* __restrict__ target,
                                                          float* __restrict__ part_l,
                                                          float* __restrict__ tcap) {
  __shared__ __bf16 As[2][128 * 32];
  __shared__ __bf16 Bs[2][128 * 32];
  __shared__ float rs2[2][128];
  int lid = (int)blockIdx.y * (int)gridDim.x + (int)blockIdx.x;
  int nid = (lid & 7) * 786 + (lid >> 3);
  int bm = (nid & 15) * 128;
  int vt = nid >> 4;
  int bn = vt * 128;
  int tid = threadIdx.x;
  int w = tid >> 6, l = tid & 63;
  int wm = (w >> 1) * 64, wn = (w & 1) * 64;
  int c = l & 15, g = l >> 4;

  auto stage = [&](int buf, int k0) {
#pragma unroll
    for (int i = 0; i < 2; ++i) {
      int L = (w * 2 + i) * 64 + l;
      int row = L >> 2, gc = L & 3;
      int gs = gc ^ GSWZ(row);
      int vrow = bn + row;
      if (vrow >= NVOC) vrow = NVOC - 1;
      const __bf16* srcA = xbf + (size_t)(bm + row) * NDIM + k0 + gs * 8;
      const __bf16* srcB = embed_bf + (size_t)vrow * NDIM + k0 + gs * 8;
      __builtin_amdgcn_global_load_lds(
          (const __attribute__((address_space(1))) void*)srcA,
          (__attribute__((address_space(3))) void*)&As[buf][(w * 2 + i) * 512], 16, 0, 0);
      __builtin_amdgcn_global_load_lds(
          (const __attribute__((address_space(1))) void*)srcB,
          (__attribute__((address_space(3))) void*)&Bs[buf][(w * 2 + i) * 512], 16, 0, 0);
    }
  };

  f32x4 acc[4][4] = {};
  stage(0, 0);
  __syncthreads();
  const int nk = NDIM / 32;
  for (int kk = 0; kk < nk; ++kk) {
    int buf = kk & 1;
    if (kk + 1 < nk) stage(buf ^ 1, (kk + 1) * 32);
    bf16x8 af[4], bfr[4];
#pragma unroll
    for (int i = 0; i < 4; ++i) {
      int row = wm + i * 16 + c;
      af[i] = *(const bf16x8*)&As[buf][row * 32 + (g ^ GSWZ(row)) * 8];
    }
#pragma unroll
    for (int j = 0; j < 4; ++j) {
      int row = wn + j * 16 + c;
      bfr[j] = *(const bf16x8*)&Bs[buf][row * 32 + (g ^ GSWZ(row)) * 8];
    }
#pragma unroll
    for (int i = 0; i < 4; ++i)
#pragma unroll
      for (int j = 0; j < 4; ++j)
        acc[i][j] = __builtin_amdgcn_mfma_f32_16x16x32_bf16(af[i], bfr[j], acc[i][j], 0, 0, 0);
    __syncthreads();
  }

#pragma unroll
  for (int i = 0; i < 4; ++i) {
#pragma unroll
    for (int rr = 0; rr < 4; ++rr) {
      int rowl = wm + i * 16 + g * 4 + rr;
      int tg = target[bm + rowl];
      float ts = 0.f;
#pragma unroll
      for (int j = 0; j < 4; ++j) {
        int vv = bn + wn + j * 16 + c;
        bool okv = vv < NVOC;
        float z = acc[i][j][rr];
        float cp = 15.f * z * rsqrtf(z * z + 225.f);
        ts += okv ? __expf(cp - CAPSH) : 0.f;
        if (okv && vv == tg) tcap[bm + rowl] = cp;
      }
      ts += __shfl_xor(ts, 1, 64);
      ts += __shfl_xor(ts, 2, 64);
      ts += __shfl_xor(ts, 4, 64);
      ts += __shfl_xor(ts, 8, 64);
      if (c == 0) rs2[w & 1][rowl] = ts;
    }
  }
  __syncthreads();
  if (tid < 128) {
    part_l[(size_t)vt * NSEQ + bm + tid] = rs2[0][tid] + rs2[1][tid];
  }
}

// ---------------- per-row reduce over vocab tiles (fixed shift) ----------------
__global__ __launch_bounds__(256) void lossrow_kernel(const float* __restrict__ part_l,
                                                      const float* __restrict__ tcap, float* __restrict__ lr) {
  int row = blockIdx.x * 256 + threadIdx.x;
  float L = 0.f;
  for (int cc = 0; cc < NVT; ++cc) L += part_l[(size_t)cc * NSEQ + row];
  lr[row] = (CAPSH + logf(L)) - tcap[row];
}

// ---------------- final mean ----------------
__global__ __launch_bounds__(256) void loss2_kernel(const float* __restrict__ lr, float* __restrict__ out) {
  int tid = threadIdx.x;
  float sum = 0.f;
  for (int t = tid; t < NSEQ; t += 256) sum += lr[t];
  __shared__ float red[256];
  red[tid] = sum; __syncthreads();
  for (int o = 128; o > 0; o >>= 1) { if (tid < o) red[tid] += red[tid + o]; __syncthreads(); }
  if (tid == 0) out[0] = red[0] / (float)NSEQ;
}

// ---------------- host driver ----------------
extern "C" void kernel_launch(void* const* d_in, const int* in_sizes, int n_in,
                              void* d_out, int out_size, void* d_ws, size_t ws_size,
                              hipStream_t stream) {
  const int* seq   = (const int*)d_in[0];
  const int* wnb   = (const int*)d_in[1];
  const int* tgt   = (const int*)d_in[2];
  const float* embed = (const float*)d_in[3];
  const float* vemb  = (const float*)d_in[4];
  const float* qkvw  = (const float*)d_in[5];
  const float* aprj  = (const float*)d_in[6];
  const float* fcw   = (const float*)d_in[7];
  const float* prjw  = (const float*)d_in[8];
  const float* scal  = (const float*)d_in[9];
  float* out = (float*)d_out;

  char* w = (char*)d_ws;
  auto alloc = [&](size_t bytes) {
    char* p = w;
    w += (bytes + 255) & ~(size_t)255;
    return p;
  };
  int* docs = (int*)alloc(NSEQ * 4);
  int* catL = (int*)alloc(NBLK * NBLK * 4);
  int* catS = (int*)alloc(NBLK * NBLK * 4);
  float* x    = (float*)alloc((size_t)NSEQ * NDIM * 4);
  float* x0   = (float*)alloc((size_t)NSEQ * NDIM * 4);
  float* sk1  = (float*)alloc((size_t)NSEQ * NDIM * 4);
  float* sk2  = (float*)alloc((size_t)NSEQ * NDIM * 4);
  float* sk3  = (float*)alloc((size_t)NSEQ * NDIM * 4);
  __bf16* qkvbf = (__bf16*)alloc((size_t)NSEQ * 3 * NHEAD * NHD * 2);
  __bf16* qbf2 = (__bf16*)alloc((size_t)NHEAD * NSEQ * NHD * 2);
  __bf16* kbf2 = (__bf16*)alloc((size_t)NHEAD * NSEQ * NHD * 2);
  __bf16* vbf2 = (__bf16*)alloc((size_t)NHEAD * NSEQ * NHD * 2);
  __bf16* vtbf = (__bf16*)alloc((size_t)NHEAD * NHD * NSEQ * 2);
  __bf16* xabf = (__bf16*)alloc((size_t)NSEQ * NDIM * 2);
  __bf16* ybf  = (__bf16*)alloc((size_t)NSEQ * NDIM * 2);
  __bf16* hbf  = (__bf16*)alloc((size_t)NSEQ * 4 * NDIM * 2);
  __bf16* xbf  = (__bf16*)alloc((size_t)NSEQ * NDIM * 2);
  float* pl   = (float*)alloc((size_t)NVT * NSEQ * 4);
  float* tc   = (float*)alloc((size_t)NSEQ * 4);
  float* lrow = (float*)alloc((size_t)NSEQ * 4);
  __bf16* embbf = (__bf16*)alloc((size_t)NVOC * NDIM * 2);
  __bf16* qkvwbf = (__bf16*)alloc((size_t)NLAY * 3 * NHEAD * NHD * NDIM * 2);
  __bf16* aprjbf = (__bf16*)alloc((size_t)NLAY * NDIM * NDIM * 2);
  __bf16* fcwbf  = (__bf16*)alloc((size_t)NLAY * 4 * NDIM * NDIM * 2);
  __bf16* prjwbf = (__bf16*)alloc((size_t)NLAY * NDIM * 4 * NDIM * 2);
  float* skips[4] = {nullptr, sk1, sk2, sk3};

  cvt_bf16_kernel<<<2048, 256, 0, stream>>>(embed, embbf, (long)NVOC * NDIM);
  cvt_bf16_kernel<<<2048, 256, 0, stream>>>(qkvw, qkvwbf, (long)NLAY * 3 * NHEAD * NHD * NDIM);
  cvt_bf16_kernel<<<2048, 256, 0, stream>>>(aprj, aprjbf, (long)NLAY * NDIM * NDIM);
  cvt_bf16_kernel<<<2048, 256, 0, stream>>>(fcw, fcwbf, (long)NLAY * 4 * NDIM * NDIM);
  cvt_bf16_kernel<<<2048, 256, 0, stream>>>(prjw, prjwbf, (long)NLAY * NDIM * 4 * NDIM);

  prep_kernel<<<1, 1024, 0, stream>>>(seq, wnb, docs, catL, catS);
  embed_rms_kernel<<<NSEQ, 256, 0, stream>>>(seq, embed, x, x0);

  const int velist[NLAY]   = {0, 1, 2, -1, -1, 0, 1, 2};
  const int skipj[NLAY]    = {-1, -1, -1, -1, -1, 3, 2, 1};
  const int maskLong[NLAY] = {1, 0, 0, 0, 1, 0, 0, 1};

  for (int i = 0; i < NLAY; ++i) {
    mixrms_kernel<<<NSEQ, 256, 0, stream>>>(x, x0, skipj[i] >= 0 ? skips[skipj[i]] : nullptr, scal, i, skipj[i], xabf);
    gemm_mfma64<3><<<dim3(NSEQ / 64, (3 * NHEAD * NHD) / 64), 256, 0, stream>>>(
        xabf, qkvwbf + (size_t)i * 3 * NHEAD * NHD * NDIM, nullptr, qkvbf, nullptr, 3 * NHEAD * NHD, NDIM);
    qkv_post_kernel<<<NHEAD * NSEQ / 4, 256, 0, stream>>>(qkvbf, vemb, seq, scal, i, velist[i], qbf2, kbf2, vbf2);
    vtrans_kernel<<<dim3(NSEQ / 64, NHD / 64, NHEAD), 256, 0, stream>>>(vbf2, vtbf);
    attn_mfma_kernel<<<dim3(NSEQ / 64, NHEAD), 512, 0, stream>>>(qbf2, kbf2, vtbf, maskLong[i] ? catL : catS, docs, ybf);
    gemm_mfma64<1><<<dim3(NSEQ / 64, NDIM / 64), 256, 0, stream>>>(
        ybf, aprjbf + (size_t)i * NDIM * NDIM, x, nullptr, nullptr, NDIM, NDIM);
    rmsbf_kernel<<<NSEQ, 256, 0, stream>>>(x, xabf);
    gemm_mfma64<2><<<dim3(NSEQ / 64, (4 * NDIM) / 64), 256, 0, stream>>>(
        xabf, fcwbf + (size_t)i * 4 * NDIM * NDIM, nullptr, hbf, nullptr, 4 * NDIM, NDIM);
    if (i >= 1 && i <= 3) {
      gemm_mfma64<4><<<dim3(NSEQ / 64, NDIM / 64), 256, 0, stream>>>(
          hbf, prjwbf + (size_t)i * NDIM * 4 * NDIM, x, nullptr, skips[i], NDIM, 4 * NDIM);
    } else {
      gemm_mfma64<1><<<dim3(NSEQ / 64, NDIM / 64), 256, 0, stream>>>(
          hbf, prjwbf + (size_t)i * NDIM * 4 * NDIM, x, nullptr, nullptr, NDIM, 4 * NDIM);
    }
  }

  rmsbf_kernel<<<NSEQ, 256, 0, stream>>>(x, xbf);
  logits_gemm_kernel<<<dim3(NSEQ / 128, NVT), 256, 0, stream>>>(xbf, embbf, tgt, pl, tc);
  lossrow_kernel<<<NSEQ / 256, 256, 0, stream>>>(pl, tc, lrow);
  loss2_kernel<<<1, 256, 0, stream>>>(lrow, out);
}

// Round 20
// 1633.705 us; speedup vs baseline: 1.0051x; 1.0051x over previous
//
#include <hip/hip_runtime.h>
#include <hip/hip_bf16.h>
#include <math.h>

#define NSEQ 2048
#define NDIM 768
#define NLAY 8
#define NHEAD 6
#define NHD 128
#define NVOC 50257
#define NBLK 16
#define BLKSZ 128
#define EOS_TOK 50256
#define EPSF 1.1920929e-07f
#define ASCALE 0.12f
#define NVT 393   // ceil(50257/128) vocab tiles
#define CAPSH 15.f   // fixed LSE shift for logits: softcap output bounded in (-15,15)
#define ATTSH 15.5f  // fixed shift for attention scores: |q.k|*0.12 <= 15.46 (rms rows)

// granule swizzle for 64B-row LDS tiles (4 x 16B granules/row)
#define GSWZ(r) (((r) ^ ((r) >> 2)) & 3)

using bf16x8 = __attribute__((ext_vector_type(8))) __bf16;
using bf16x4 = __attribute__((ext_vector_type(4))) __bf16;
using f32x4  = __attribute__((ext_vector_type(4))) float;

__device__ __forceinline__ __bf16 tobf(float x) {
  __hip_bfloat16 h = __float2bfloat16(x);
  return *reinterpret_cast<__bf16*>(&h);
}
__device__ __forceinline__ float frombf(__bf16 x) {
  __hip_bfloat16 h = *reinterpret_cast<__hip_bfloat16*>(&x);
  return __bfloat162float(h);
}

// ---------------- f32 -> bf16 bulk convert ----------------
__global__ __launch_bounds__(256) void cvt_bf16_kernel(const float* __restrict__ in, __bf16* __restrict__ out,
                                                       long n) {
  long i = ((long)blockIdx.x * blockDim.x + threadIdx.x) * 4;
  long stride = (long)gridDim.x * blockDim.x * 4;
  for (; i < n; i += stride) {
    float4 v = *(const float4*)(in + i);
    bf16x4 o;
    o[0] = tobf(v.x); o[1] = tobf(v.y); o[2] = tobf(v.z); o[3] = tobf(v.w);
    *(bf16x4*)(out + i) = o;
  }
}

// ---------------- prep: docs cumsum + block mask categories ----------------
__global__ __launch_bounds__(1024) void prep_kernel(const int* __restrict__ seq, const int* __restrict__ wptr,
                                                    int* __restrict__ docs, int* __restrict__ catL,
                                                    int* __restrict__ catS) {
  __shared__ int f[NSEQ];
  __shared__ int g[NSEQ];
  int tid = threadIdx.x;
  for (int i = tid; i < NSEQ; i += 1024) f[i] = (seq[i] == EOS_TOK) ? 1 : 0;
  __syncthreads();
  int* a = f; int* b = g;
  for (int off = 1; off < NSEQ; off <<= 1) {
    for (int i = tid; i < NSEQ; i += 1024) {
      int v = a[i];
      if (i >= off) v += a[i - off];
      b[i] = v;
    }
    __syncthreads();
    int* t = a; a = b; b = t;
  }
  for (int i = tid; i < NSEQ; i += 1024) docs[i] = a[i];
  __syncthreads();
  if (tid == 0) {
    int dl[NBLK], dh[NBLK];
    for (int bi = 0; bi < NBLK; ++bi) { dl[bi] = a[bi * BLKSZ]; dh[bi] = a[bi * BLKSZ + BLKSZ - 1]; }
    int W = *wptr;
    for (int pass = 0; pass < 2; ++pass) {
      int w = (pass == 0) ? W : (W / 2);
      int* cat = (pass == 0) ? catL : catS;
      for (int i = 0; i < NBLK; ++i) {
        int allr[NBLK], partr[NBLK];
        int nf = 0, np = 0;
        for (int j = 0; j < NBLK; ++j) {
          int any_ = (i >= j) && (dl[i] <= dh[j]) && (dh[i] >= dl[j]);
          int all_ = (i > j) && (dl[i] == dh[j]) && (dh[i] == dl[j]);
          allr[j] = all_; partr[j] = any_ && !all_;
          nf += all_; np += partr[j];
        }
        int kcf = min(nf, w - 1);
        int kcp = min(np, max(w - nf, 1));
        int cf = 0, cp = 0;
        for (int j = NBLK - 1; j >= 0; --j) {
          int cv = 0;
          if (allr[j]) { cf++; if (cf <= kcf) cv = 2; }
          if (partr[j]) { cp++; if (cp <= kcp) cv = 1; }
          cat[i * NBLK + j] = cv;
        }
      }
    }
  }
}

// ---------------- embedding gather + rms -> x, x0 ----------------
__global__ __launch_bounds__(256) void embed_rms_kernel(const int* __restrict__ seq, const float* __restrict__ embed,
                                                        float* __restrict__ x, float* __restrict__ x0) {
  int s = blockIdx.x;
  int tid = threadIdx.x;
  const float* row = embed + (size_t)seq[s] * NDIM;
  float v0 = row[tid], v1 = row[tid + 256], v2 = row[tid + 512];
  float ss = v0 * v0 + v1 * v1 + v2 * v2;
  __shared__ float red[256];
  red[tid] = ss; __syncthreads();
  for (int o = 128; o > 0; o >>= 1) { if (tid < o) red[tid] += red[tid + o]; __syncthreads(); }
  float sc = rsqrtf(red[0] / (float)NDIM + EPSF);
  size_t base = (size_t)s * NDIM;
  float o0 = v0 * sc, o1 = v1 * sc, o2 = v2 * sc;
  x[base + tid] = o0; x[base + tid + 256] = o1; x[base + tid + 512] = o2;
  x0[base + tid] = o0; x0[base + tid + 256] = o1; x0[base + tid + 512] = o2;
}

// ---------------- row rms -> bf16 ----------------
__global__ __launch_bounds__(256) void rmsbf_kernel(const float* __restrict__ x, __bf16* __restrict__ xb) {
  int s = blockIdx.x;
  int tid = threadIdx.x;
  size_t base = (size_t)s * NDIM;
  float v0 = x[base + tid], v1 = x[base + tid + 256], v2 = x[base + tid + 512];
  float ss = v0 * v0 + v1 * v1 + v2 * v2;
  __shared__ float red[256];
  red[tid] = ss; __syncthreads();
  for (int o = 128; o > 0; o >>= 1) { if (tid < o) red[tid] += red[tid + o]; __syncthreads(); }
  float sc = rsqrtf(red[0] / (float)NDIM + EPSF);
  xb[base + tid] = tobf(v0 * sc); xb[base + tid + 256] = tobf(v1 * sc); xb[base + tid + 512] = tobf(v2 * sc);
}

// ---------------- fused residual mix + rms->bf16 ----------------
__global__ __launch_bounds__(256) void mixrms_kernel(float* __restrict__ x, const float* __restrict__ x0,
                                                     const float* __restrict__ skip, const float* __restrict__ scal,
                                                     int li, int sj, __bf16* __restrict__ xb) {
  float lam0 = scal[NLAY + 2 * li], lam1 = scal[NLAY + 2 * li + 1];
  float sw = (sj >= 0) ? scal[sj] : 0.f;
  int s = blockIdx.x;
  int tid = threadIdx.x;
  size_t base = (size_t)s * NDIM;
  float xv[3], ov[3], nv[3];
  xv[0] = x[base + tid]; xv[1] = x[base + tid + 256]; xv[2] = x[base + tid + 512];
  ov[0] = x0[base + tid]; ov[1] = x0[base + tid + 256]; ov[2] = x0[base + tid + 512];
  if (skip) {
    nv[0] = lam0 * (xv[0] + sw * skip[base + tid])       + lam1 * ov[0];
    nv[1] = lam0 * (xv[1] + sw * skip[base + tid + 256]) + lam1 * ov[1];
    nv[2] = lam0 * (xv[2] + sw * skip[base + tid + 512]) + lam1 * ov[2];
  } else {
    nv[0] = lam0 * xv[0] + lam1 * ov[0];
    nv[1] = lam0 * xv[1] + lam1 * ov[1];
    nv[2] = lam0 * xv[2] + lam1 * ov[2];
  }
  x[base + tid] = nv[0]; x[base + tid + 256] = nv[1]; x[base + tid + 512] = nv[2];
  float ss = nv[0] * nv[0] + nv[1] * nv[1] + nv[2] * nv[2];
  __shared__ float red[256];
  red[tid] = ss; __syncthreads();
  for (int o = 128; o > 0; o >>= 1) { if (tid < o) red[tid] += red[tid + o]; __syncthreads(); }
  float sc = rsqrtf(red[0] / (float)NDIM + EPSF);
  xb[base + tid] = tobf(nv[0] * sc); xb[base + tid + 256] = tobf(nv[1] * sc); xb[base + tid + 512] = tobf(nv[2] * sc);
}

// ---------------- bf16 MFMA GEMM 64x64, BK=64, global_load_lds dbuf, swizzled LDS ---------
// MODE 0: store f32; 1: += f32; 2: relu^2->bf16; 3: store bf16; 4: += f32 AND copy to Sk.
template <int MODE>
__global__ __launch_bounds__(256) void gemm_mfma64(const __bf16* __restrict__ A, const __bf16* __restrict__ B,
                                                   float* __restrict__ Cf, __bf16* __restrict__ Cb,
                                                   float* __restrict__ Sk, int N, int K) {
  __shared__ __bf16 As[2][64 * 64];
  __shared__ __bf16 Bs[2][64 * 64];
  int bm = blockIdx.x * 64, bn = blockIdx.y * 64;
  int tid = threadIdx.x;
  int w = tid >> 6, l = tid & 63;
  int wm = (w >> 1) * 32, wn = (w & 1) * 32;
  int c = l & 15, g = l >> 4;

  auto stage = [&](int buf, int k0) {
#pragma unroll
    for (int i = 0; i < 2; ++i) {
      int L = (w * 2 + i) * 64 + l;   // granule 0..511
      int row = L >> 3, gl = L & 7;
      int gs = gl ^ (row & 7);
      const __bf16* srcA = A + (size_t)(bm + row) * K + k0 + gs * 8;
      const __bf16* srcB = B + (size_t)(bn + row) * K + k0 + gs * 8;
      __builtin_amdgcn_global_load_lds(
          (const __attribute__((address_space(1))) void*)srcA,
          (__attribute__((address_space(3))) void*)&As[buf][(w * 2 + i) * 512], 16, 0, 0);
      __builtin_amdgcn_global_load_lds(
          (const __attribute__((address_space(1))) void*)srcB,
          (__attribute__((address_space(3))) void*)&Bs[buf][(w * 2 + i) * 512], 16, 0, 0);
    }
  };

  f32x4 acc[2][2] = {};
  stage(0, 0);
  __syncthreads();
  int nk = K >> 6;
  for (int kk = 0; kk < nk; ++kk) {
    int buf = kk & 1;
    if (kk + 1 < nk) stage(buf ^ 1, (kk + 1) * 64);
#pragma unroll
    for (int ks = 0; ks < 2; ++ks) {
      bf16x8 af[2], bfr[2];
#pragma unroll
      for (int i = 0; i < 2; ++i) {
        int row = wm + i * 16 + c;
        af[i] = *(const bf16x8*)&As[buf][row * 64 + ((ks * 4 + g) ^ (row & 7)) * 8];
      }
#pragma unroll
      for (int j = 0; j < 2; ++j) {
        int row = wn + j * 16 + c;
        bfr[j] = *(const bf16x8*)&Bs[buf][row * 64 + ((ks * 4 + g) ^ (row & 7)) * 8];
      }
#pragma unroll
      for (int i = 0; i < 2; ++i)
#pragma unroll
        for (int j = 0; j < 2; ++j)
          acc[i][j] = __builtin_amdgcn_mfma_f32_16x16x32_bf16(af[i], bfr[j], acc[i][j], 0, 0, 0);
    }
    __syncthreads();
  }
#pragma unroll
  for (int i = 0; i < 2; ++i)
#pragma unroll
    for (int j = 0; j < 2; ++j)
#pragma unroll
      for (int rr = 0; rr < 4; ++rr) {
        int row = bm + wm + i * 16 + g * 4 + rr;
        int col = bn + wn + j * 16 + c;
        size_t ci = (size_t)row * N + col;
        float z = acc[i][j][rr];
        if (MODE == 0) Cf[ci] = z;
        else if (MODE == 1) Cf[ci] += z;
        else if (MODE == 2) { float r = fmaxf(z, 0.f); Cb[ci] = tobf(r * r); }
        else if (MODE == 3) Cb[ci] = tobf(z);
        else { float s = Cf[ci] + z; Cf[ci] = s; Sk[ci] = s; }
      }
}

// ---------------- qkv post: wave per (s,h); bf16 in, bf16 q,k,v out ----------------
__global__ __launch_bounds__(256) void qkv_post_kernel(const __bf16* __restrict__ qkv, const float* __restrict__ vemb,
                                                       const int* __restrict__ seq, const float* __restrict__ scal,
                                                       int li, int ve_idx,
                                                       __bf16* __restrict__ qo, __bf16* __restrict__ ko,
                                                       __bf16* __restrict__ vo) {
  int p = blockIdx.x * 4 + (threadIdx.x >> 6);  // p = h*NSEQ + s
  int l = threadIdx.x & 63;
  int h = p >> 11;
  int s = p & (NSEQ - 1);
  float sal0 = scal[3 * NLAY + 2 * li], sal1 = scal[3 * NLAY + 2 * li + 1];
  float fr = (l < 32) ? powf(1.0f / 1024.0f, (float)l * (1.0f / 31.0f)) : 0.f;
  float th = (float)s * fr;
  float cth = cosf(th), sth = sinf(th);
  size_t rb = (size_t)s * (3 * NHEAD * NHD) + h * NHD;
  float q0 = frombf(qkv[rb + l]),                 q1 = frombf(qkv[rb + l + 64]);
  float k0 = frombf(qkv[rb + NHEAD * NHD + l]),   k1 = frombf(qkv[rb + NHEAD * NHD + l + 64]);
  float v0 = frombf(qkv[rb + 2 * NHEAD * NHD + l]), v1 = frombf(qkv[rb + 2 * NHEAD * NHD + l + 64]);
  float ssq = q0 * q0 + q1 * q1;
  float ssk = k0 * k0 + k1 * k1;
#pragma unroll
  for (int o = 1; o < 64; o <<= 1) {
    ssq += __shfl_xor(ssq, o, 64);
    ssk += __shfl_xor(ssk, o, 64);
  }
  float scq = rsqrtf(ssq / (float)NHD + EPSF);
  float sck = rsqrtf(ssk / (float)NHD + EPSF);
  float qn0 = q0 * scq, qn1 = q1 * scq;
  float kn0 = k0 * sck, kn1 = k1 * sck;
  float oq0 = qn0 * cth + qn1 * sth, oq1 = -qn0 * sth + qn1 * cth;
  float ok0 = kn0 * cth + kn1 * sth, ok1 = -kn0 * sth + kn1 * cth;
  float ov0 = sal0 * v0, ov1 = sal0 * v1;
  if (ve_idx >= 0) {
    const float* ver = vemb + ((size_t)ve_idx * NVOC + seq[s]) * NDIM + h * NHD;
    ov0 += sal1 * ver[l];
    ov1 += sal1 * ver[l + 64];
  }
  size_t oo = ((size_t)h * NSEQ + s) * NHD;
  qo[oo + l] = tobf(oq0); qo[oo + l + 64] = tobf(oq1);
  ko[oo + l] = tobf(ok0); ko[oo + l + 64] = tobf(ok1);
  vo[oo + l] = tobf(ov0); vo[oo + l + 64] = tobf(ov1);
}

// ---------------- V transpose: [h][s][d] -> [h][d][s] (bf16) ----------------
__global__ __launch_bounds__(256) void vtrans_kernel(const __bf16* __restrict__ v, __bf16* __restrict__ vt) {
  int st = blockIdx.x * 64, dt = blockIdx.y * 64, h = blockIdx.z;
  __shared__ __bf16 t[64][65];
  int tid = threadIdx.x;
  for (int e = tid; e < 4096; e += 256) {
    int s = e >> 6, d = e & 63;
    t[s][d] = v[((size_t)h * NSEQ + st + s) * NHD + dt + d];
  }
  __syncthreads();
  for (int e = tid; e < 512; e += 256) {
    int d = e >> 3, s0 = (e & 7) * 8;
    bf16x8 ov;
#pragma unroll
    for (int i = 0; i < 8; ++i) ov[i] = t[s0 + i][d];
    *(bf16x8*)(vt + ((size_t)h * NHD + dt + d) * NSEQ + st + s0) = ov;
  }
}

// ---------------- MFMA flash attention v6: fixed-shift softmax (no online max) ----------
// Scores bounded: |q.k|*ASCALE <= sqrt(128)^2*0.12 = 15.36 < ATTSH -> p = exp(s-ATTSH) <= 1.
// O = sum(p*V)/sum(p) is exactly softmax (shift cancels). No max tracking, no rescale.
// 4 waves, wave-pair tile-parity split; plain-sum merge at end.
__global__ __launch_bounds__(256) void attn_mfma_kernel(const __bf16* __restrict__ qb, const __bf16* __restrict__ kb,
                                                        const __bf16* __restrict__ vt, const int* __restrict__ cat,
                                                        const int* __restrict__ docs, __bf16* __restrict__ y) {
  int qb32 = (int)gridDim.x - 1 - (int)blockIdx.x;
  int h = blockIdx.y;
  int tid = threadIdx.x;
  int wq = tid >> 6;      // 0..3
  int pr = wq >> 1;       // tile-parity pair
  int sub = wq & 1;       // q-row half within pair
  int l = tid & 63;
  int c = l & 15, g = l >> 4;
  int q0 = qb32 * 32 + sub * 16;
  int qB = qb32 >> 2;

  __shared__ __align__(16) char arena[65536];
  __bf16* Ks  = (__bf16*)arena;
  __bf16* Vts = (__bf16*)(arena + 32768);
  __shared__ __bf16 Ps[4][16 * 32];
  __shared__ int kvs[64];
  __shared__ int kvc[64];
  __shared__ int nact_s;

  if (tid == 0) {
    int n = 0;
    for (int kv = 0; kv <= qb32; ++kv) {
      int cc = cat[qB * NBLK + (kv >> 2)];
      if (cc) { kvs[n] = kv; kvc[n] = cc; ++n; }
    }
    nact_s = n;
  }

  bf16x8 qf[4];
#pragma unroll
  for (int ks = 0; ks < 4; ++ks)
    qf[ks] = *(const bf16x8*)(qb + ((size_t)h * NSEQ + q0 + c) * NHD + ks * 32 + g * 8);

  int qd[4];
#pragma unroll
  for (int rr = 0; rr < 4; ++rr) qd[rr] = docs[q0 + g * 4 + rr];

  float lden[4] = {0.f, 0.f, 0.f, 0.f};
  f32x4 oacc[8] = {};

  __syncthreads();
  int nact = nact_s;
  int nit = (nact + 1) >> 1;

  auto stage = [&](int ti, int bufi) {
    int kv = kvs[ti];
#pragma unroll
    for (int i = 0; i < 4; ++i) {
      int L = (sub * 4 + i) * 64 + l;
      int krow = L >> 4, gl = L & 15;
      int gs = gl ^ (krow & 7);
      const __bf16* srcK = kb + ((size_t)h * NSEQ + kv * 32 + krow) * NHD + gs * 8;
      __builtin_amdgcn_global_load_lds(
          (const __attribute__((address_space(1))) void*)srcK,
          (__attribute__((address_space(3))) void*)&Ks[(pr * 2 + bufi) * 4096 + (sub * 4 + i) * 512], 16, 0, 0);
      int drow = L >> 2, gk = L & 3;
      const __bf16* srcV = vt + ((size_t)h * NHD + drow) * NSEQ + kv * 32 + gk * 8;
      __builtin_amdgcn_global_load_lds(
          (const __attribute__((address_space(1))) void*)srcV,
          (__attribute__((address_space(3))) void*)&Vts[(pr * 2 + bufi) * 4096 + (sub * 4 + i) * 512], 16, 0, 0);
    }
  };

  if (pr < nact) stage(pr, 0);
  __syncthreads();

  for (int it = 0; it < nit; ++it) {
    int buf = it & 1;
    int tin = 2 * (it + 1) + pr;
    if (tin < nact) stage(tin, buf ^ 1);
    int ti = 2 * it + pr;
    if (ti < nact) {
      int kv = kvs[ti], cc = kvc[ti];
      int k0 = kv * 32;
      const __bf16* Kb = &Ks[(pr * 2 + buf) * 4096];
      const __bf16* Vb = &Vts[(pr * 2 + buf) * 4096];

      f32x4 sacc[2] = {};
#pragma unroll
      for (int ks = 0; ks < 4; ++ks) {
#pragma unroll
        for (int j = 0; j < 2; ++j) {
          int row = j * 16 + c;
          int gi = (ks * 4 + g) ^ (row & 7);
          bf16x8 kf = *(const bf16x8*)&Kb[row * 128 + gi * 8];
          sacc[j] = __builtin_amdgcn_mfma_f32_16x16x32_bf16(qf[ks], kf, sacc[j], 0, 0, 0);
        }
      }
      // fixed-shift probabilities (masked -> 0), per-row partial sum
      float sc[2][4];
      float psum[4] = {0.f, 0.f, 0.f, 0.f};
#pragma unroll
      for (int j = 0; j < 2; ++j) {
        int key = k0 + j * 16 + c;
        int kdj = docs[key];
#pragma unroll
        for (int rr = 0; rr < 4; ++rr) {
          int qrow = q0 + g * 4 + rr;
          bool ok = (cc == 2) || ((key <= qrow) && (kdj == qd[rr]));
          float pv = ok ? __expf(sacc[j][rr] * ASCALE - ATTSH) : 0.f;
          sc[j][rr] = pv;
          psum[rr] += pv;
        }
      }
#pragma unroll
      for (int rr = 0; rr < 4; ++rr) {
        psum[rr] += __shfl_xor(psum[rr], 1, 64);
        psum[rr] += __shfl_xor(psum[rr], 2, 64);
        psum[rr] += __shfl_xor(psum[rr], 4, 64);
        psum[rr] += __shfl_xor(psum[rr], 8, 64);
        lden[rr] += psum[rr];
      }
#pragma unroll
      for (int j = 0; j < 2; ++j)
#pragma unroll
        for (int rr = 0; rr < 4; ++rr)
          Ps[wq][(g * 4 + rr) * 32 + j * 16 + c] = tobf(sc[j][rr]);
      asm volatile("s_waitcnt lgkmcnt(0)" ::: "memory");
      bf16x8 pf = *(const bf16x8*)&Ps[wq][c * 32 + g * 8];
#pragma unroll
      for (int nt = 0; nt < 8; ++nt) {
        bf16x8 vf = *(const bf16x8*)&Vb[(nt * 16 + c) * 32 + g * 8];
        oacc[nt] = __builtin_amdgcn_mfma_f32_16x16x32_bf16(pf, vf, oacc[nt], 0, 0, 0);
      }
    }
    __syncthreads();
  }

  // intra-block merge: plain sums (fixed shift -> no weighting needed)
  float* mrg = (float*)arena;  // [sub*64+l][36]: lden[4], oacc[8][4]
  if (pr == 1) {
    int base = (sub * 64 + l) * 36;
#pragma unroll
    for (int rr = 0; rr < 4; ++rr) mrg[base + rr] = lden[rr];
#pragma unroll
    for (int nt = 0; nt < 8; ++nt)
#pragma unroll
      for (int rr = 0; rr < 4; ++rr) mrg[base + 4 + nt * 4 + rr] = oacc[nt][rr];
  }
  __syncthreads();
  if (pr == 0) {
    int base = (sub * 64 + l) * 36;
    float inv[4];
#pragma unroll
    for (int rr = 0; rr < 4; ++rr) {
      float L = lden[rr] + mrg[base + rr];
      inv[rr] = (L > 0.f) ? 1.f / L : 0.f;
    }
#pragma unroll
    for (int nt = 0; nt < 8; ++nt)
#pragma unroll
      for (int rr = 0; rr < 4; ++rr) {
        int qrow = q0 + g * 4 + rr;
        float o = oacc[nt][rr] + mrg[base + 4 + nt * 4 + rr];
        y[(size_t)qrow * NDIM + h * NHD + nt * 16 + c] = tobf(o * inv[rr]);
      }
  }
}

// ---------------- logits GEMM + fused softcap/fixed-shift-LSE epilogue, XCD-swizzled ------
__global__ __launch_bounds__(256) void logits_gemm_kernel(const __bf16* __restrict__ xbf,
                                                          const __bf16* __restrict__ embed_bf,
                                                          const int* __restrict__ target,
                                                          float* __restrict__ part_l,
                                                          float* __restrict__ tcap) {
  __shared__ __bf16 As[2][128 * 32];
  __shared__ __bf16 Bs[2][128 * 32];
  __shared__ float rs2[2][128];
  int lid = (int)blockIdx.y * (int)gridDim.x + (int)blockIdx.x;
  int nid = (lid & 7) * 786 + (lid >> 3);
  int bm = (nid & 15) * 128;
  int vt = nid >> 4;
  int bn = vt * 128;
  int tid = threadIdx.x;
  int w = tid >> 6, l = tid & 63;
  int wm = (w >> 1) * 64, wn = (w & 1) * 64;
  int c = l & 15, g = l >> 4;

  auto stage = [&](int buf, int k0) {
#pragma unroll
    for (int i = 0; i < 2; ++i) {
      int L = (w * 2 + i) * 64 + l;
      int row = L >> 2, gc = L & 3;
      int gs = gc ^ GSWZ(row);
      int vrow = bn + row;
      if (vrow >= NVOC) vrow = NVOC - 1;
      const __bf16* srcA = xbf + (size_t)(bm + row) * NDIM + k0 + gs * 8;
      const __bf16* srcB = embed_bf + (size_t)vrow * NDIM + k0 + gs * 8;
      __builtin_amdgcn_global_load_lds(
          (const __attribute__((address_space(1))) void*)srcA,
          (__attribute__((address_space(3))) void*)&As[buf][(w * 2 + i) * 512], 16, 0, 0);
      __builtin_amdgcn_global_load_lds(
          (const __attribute__((address_space(1))) void*)srcB,
          (__attribute__((address_space(3))) void*)&Bs[buf][(w * 2 + i) * 512], 16, 0, 0);
    }
  };

  f32x4 acc[4][4] = {};
  stage(0, 0);
  __syncthreads();
  const int nk = NDIM / 32;
  for (int kk = 0; kk < nk; ++kk) {
    int buf = kk & 1;
    if (kk + 1 < nk) stage(buf ^ 1, (kk + 1) * 32);
    bf16x8 af[4], bfr[4];
#pragma unroll
    for (int i = 0; i < 4; ++i) {
      int row = wm + i * 16 + c;
      af[i] = *(const bf16x8*)&As[buf][row * 32 + (g ^ GSWZ(row)) * 8];
    }
#pragma unroll
    for (int j = 0; j < 4; ++j) {
      int row = wn + j * 16 + c;
      bfr[j] = *(const bf16x8*)&Bs[buf][row * 32 + (g ^ GSWZ(row)) * 8];
    }
#pragma unroll
    for (int i = 0; i < 4; ++i)
#pragma unroll
      for (int j = 0; j < 4; ++j)
        acc[i][j] = __builtin_amdgcn_mfma_f32_16x16x32_bf16(af[i], bfr[j], acc[i][j], 0, 0, 0);
    __syncthreads();
  }

#pragma unroll
  for (int i = 0; i < 4; ++i) {
#pragma unroll
    for (int rr = 0; rr < 4; ++rr) {
      int rowl = wm + i * 16 + g * 4 + rr;
      int tg = target[bm + rowl];
      float ts = 0.f;
#pragma unroll
      for (int j = 0; j < 4; ++j) {
        int vv = bn + wn + j * 16 + c;
        bool okv = vv < NVOC;
        float z = acc[i][j][rr];
        float cp = 15.f * z * rsqrtf(z * z + 225.f);
        ts += okv ? __expf(cp - CAPSH) : 0.f;
        if (okv && vv == tg) tcap[bm + rowl] = cp;
      }
      ts += __shfl_xor(ts, 1, 64);
      ts += __shfl_xor(ts, 2, 64);
      ts += __shfl_xor(ts, 4, 64);
      ts += __shfl_xor(ts, 8, 64);
      if (c == 0) rs2[w & 1][rowl] = ts;
    }
  }
  __syncthreads();
  if (tid < 128) {
    part_l[(size_t)vt * NSEQ + bm + tid] = rs2[0][tid] + rs2[1][tid];
  }
}

// ---------------- per-row reduce over vocab tiles (fixed shift) ----------------
__global__ __launch_bounds__(256) void lossrow_kernel(const float* __restrict__ part_l,
                                                      const float* __restrict__ tcap, float* __restrict__ lr) {
  int row = blockIdx.x * 256 + threadIdx.x;
  float L = 0.f;
  for (int cc = 0; cc < NVT; ++cc) L += part_l[(size_t)cc * NSEQ + row];
  lr[row] = (CAPSH + logf(L)) - tcap[row];
}

// ---------------- final mean ----------------
__global__ __launch_bounds__(256) void loss2_kernel(const float* __restrict__ lr, float* __restrict__ out) {
  int tid = threadIdx.x;
  float sum = 0.f;
  for (int t = tid; t < NSEQ; t += 256) sum += lr[t];
  __shared__ float red[256];
  red[tid] = sum; __syncthreads();
  for (int o = 128; o > 0; o >>= 1) { if (tid < o) red[tid] += red[tid + o]; __syncthreads(); }
  if (tid == 0) out[0] = red[0] / (float)NSEQ;
}

// ---------------- host driver ----------------
extern "C" void kernel_launch(void* const* d_in, const int* in_sizes, int n_in,
                              void* d_out, int out_size, void* d_ws, size_t ws_size,
                              hipStream_t stream) {
  const int* seq   = (const int*)d_in[0];
  const int* wnb   = (const int*)d_in[1];
  const int* tgt   = (const int*)d_in[2];
  const float* embed = (const float*)d_in[3];
  const float* vemb  = (const float*)d_in[4];
  const float* qkvw  = (const float*)d_in[5];
  const float* aprj  = (const float*)d_in[6];
  const float* fcw   = (const float*)d_in[7];
  const float* prjw  = (const float*)d_in[8];
  const float* scal  = (const float*)d_in[9];
  float* out = (float*)d_out;

  char* w = (char*)d_ws;
  auto alloc = [&](size_t bytes) {
    char* p = w;
    w += (bytes + 255) & ~(size_t)255;
    return p;
  };
  int* docs = (int*)alloc(NSEQ * 4);
  int* catL = (int*)alloc(NBLK * NBLK * 4);
  int* catS = (int*)alloc(NBLK * NBLK * 4);
  float* x    = (float*)alloc((size_t)NSEQ * NDIM * 4);
  float* x0   = (float*)alloc((size_t)NSEQ * NDIM * 4);
  float* sk1  = (float*)alloc((size_t)NSEQ * NDIM * 4);
  float* sk2  = (float*)alloc((size_t)NSEQ * NDIM * 4);
  float* sk3  = (float*)alloc((size_t)NSEQ * NDIM * 4);
  __bf16* qkvbf = (__bf16*)alloc((size_t)NSEQ * 3 * NHEAD * NHD * 2);
  __bf16* qbf2 = (__bf16*)alloc((size_t)NHEAD * NSEQ * NHD * 2);
  __bf16* kbf2 = (__bf16*)alloc((size_t)NHEAD * NSEQ * NHD * 2);
  __bf16* vbf2 = (__bf16*)alloc((size_t)NHEAD * NSEQ * NHD * 2);
  __bf16* vtbf = (__bf16*)alloc((size_t)NHEAD * NHD * NSEQ * 2);
  __bf16* xabf = (__bf16*)alloc((size_t)NSEQ * NDIM * 2);
  __bf16* ybf  = (__bf16*)alloc((size_t)NSEQ * NDIM * 2);
  __bf16* hbf  = (__bf16*)alloc((size_t)NSEQ * 4 * NDIM * 2);
  __bf16* xbf  = (__bf16*)alloc((size_t)NSEQ * NDIM * 2);
  float* pl   = (float*)alloc((size_t)NVT * NSEQ * 4);
  float* tc   = (float*)alloc((size_t)NSEQ * 4);
  float* lrow = (float*)alloc((size_t)NSEQ * 4);
  __bf16* embbf = (__bf16*)alloc((size_t)NVOC * NDIM * 2);
  __bf16* qkvwbf = (__bf16*)alloc((size_t)NLAY * 3 * NHEAD * NHD * NDIM * 2);
  __bf16* aprjbf = (__bf16*)alloc((size_t)NLAY * NDIM * NDIM * 2);
  __bf16* fcwbf  = (__bf16*)alloc((size_t)NLAY * 4 * NDIM * NDIM * 2);
  __bf16* prjwbf = (__bf16*)alloc((size_t)NLAY * NDIM * 4 * NDIM * 2);
  float* skips[4] = {nullptr, sk1, sk2, sk3};

  cvt_bf16_kernel<<<2048, 256, 0, stream>>>(embed, embbf, (long)NVOC * NDIM);
  cvt_bf16_kernel<<<2048, 256, 0, stream>>>(qkvw, qkvwbf, (long)NLAY * 3 * NHEAD * NHD * NDIM);
  cvt_bf16_kernel<<<2048, 256, 0, stream>>>(aprj, aprjbf, (long)NLAY * NDIM * NDIM);
  cvt_bf16_kernel<<<2048, 256, 0, stream>>>(fcw, fcwbf, (long)NLAY * 4 * NDIM * NDIM);
  cvt_bf16_kernel<<<2048, 256, 0, stream>>>(prjw, prjwbf, (long)NLAY * NDIM * 4 * NDIM);

  prep_kernel<<<1, 1024, 0, stream>>>(seq, wnb, docs, catL, catS);
  embed_rms_kernel<<<NSEQ, 256, 0, stream>>>(seq, embed, x, x0);

  const int velist[NLAY]   = {0, 1, 2, -1, -1, 0, 1, 2};
  const int skipj[NLAY]    = {-1, -1, -1, -1, -1, 3, 2, 1};
  const int maskLong[NLAY] = {1, 0, 0, 0, 1, 0, 0, 1};

  for (int i = 0; i < NLAY; ++i) {
    mixrms_kernel<<<NSEQ, 256, 0, stream>>>(x, x0, skipj[i] >= 0 ? skips[skipj[i]] : nullptr, scal, i, skipj[i], xabf);
    gemm_mfma64<3><<<dim3(NSEQ / 64, (3 * NHEAD * NHD) / 64), 256, 0, stream>>>(
        xabf, qkvwbf + (size_t)i * 3 * NHEAD * NHD * NDIM, nullptr, qkvbf, nullptr, 3 * NHEAD * NHD, NDIM);
    qkv_post_kernel<<<NHEAD * NSEQ / 4, 256, 0, stream>>>(qkvbf, vemb, seq, scal, i, velist[i], qbf2, kbf2, vbf2);
    vtrans_kernel<<<dim3(NSEQ / 64, NHD / 64, NHEAD), 256, 0, stream>>>(vbf2, vtbf);
    attn_mfma_kernel<<<dim3(NSEQ / 32, NHEAD), 256, 0, stream>>>(qbf2, kbf2, vtbf, maskLong[i] ? catL : catS, docs, ybf);
    gemm_mfma64<1><<<dim3(NSEQ / 64, NDIM / 64), 256, 0, stream>>>(
        ybf, aprjbf + (size_t)i * NDIM * NDIM, x, nullptr, nullptr, NDIM, NDIM);
    rmsbf_kernel<<<NSEQ, 256, 0, stream>>>(x, xabf);
    gemm_mfma64<2><<<dim3(NSEQ / 64, (4 * NDIM) / 64), 256, 0, stream>>>(
        xabf, fcwbf + (size_t)i * 4 * NDIM * NDIM, nullptr, hbf, nullptr, 4 * NDIM, NDIM);
    if (i >= 1 && i <= 3) {
      gemm_mfma64<4><<<dim3(NSEQ / 64, NDIM / 64), 256, 0, stream>>>(
          hbf, prjwbf + (size_t)i * NDIM * 4 * NDIM, x, nullptr, skips[i], NDIM, 4 * NDIM);
    } else {
      gemm_mfma64<1><<<dim3(NSEQ / 64, NDIM / 64), 256, 0, stream>>>(
          hbf, prjwbf + (size_t)i * NDIM * 4 * NDIM, x, nullptr, nullptr, NDIM, 4 * NDIM);
    }
  }

  rmsbf_kernel<<<NSEQ, 256, 0, stream>>>(x, xbf);
  logits_gemm_kernel<<<dim3(NSEQ / 128, NVT), 256, 0, stream>>>(xbf, embbf, tgt, pl, tc);
  lossrow_kernel<<<NSEQ / 256, 256, 0, stream>>>(pl, tc, lrow);
  loss2_kernel<<<1, 256, 0, stream>>>(lrow, out);
}